// Round 9
// baseline (3431.430 us; speedup 1.0000x reference)
//
#include <hip/hip_runtime.h>

// EncoderRNN: bidirectional GRU, T=1024, B=64, H=256, V=32000, fp32.
// Round 15 = Round 14 with the launch-bounds bug fixed. R14's
// __launch_bounds__(1024, 8) demanded 8 waves/EU min => two 16-wave blocks
// co-resident => 64-VGPR cap => catastrophic spill (af[3][8] alone is 96
// VGPRs) => bench failure. Correct: (1024, 4) = one 16-wave block/CU,
// 128-VGPR cap (matches every working revision's budget).
//
// R14 design, unchanged:
//  - scan block = 1024 threads / 16 waves (4 waves/SIMD). Wave wv owns
//    gate-tiles tl = g*16 + wv (af[3][8]); 4 independent serial chains
//    interleave per SIMD so one wave's res/epilogue hides under another's
//    MFMA tail (R7 showed the gap is per-wave serial chains, not barriers
//    or memory latency).
//  - MFMA kc=0 accumulates onto a persistent ZERO quad (D!=C legal) — no
//    per-step accumulator zero-init.
//  - epilogue: lanes 0..31 own (b = lane>>4, j = wv*16 + lane&15).
//  - xg branch: 16 waves (wave w: m-tile w&3, n-tiles 12*(w>>2)..+12);
//    same kc order -> bitwise-identical xg.
//  - fusion, palindromic chunks {64,224,224,224,224,64}, rcp activations,
//    r/z bias folded into xg, parity-double-buffered hbf, lgkm-only step
//    barrier.
//
// ws layout (float offsets):
//   hcar  : 0        [dir][b][j] 2*64*256 = 32768
//   pA    : 32768    scan Whh bf16 A-frags [dir][tile48][kc8][lane64][jj8] = 2*196608 ush
//   pWihB : 229376   xg Wih bf16 B-frags  [dir][kc8][nt48][lane64][jj8]   = 2*196608 ush
//   embB  : 425984   bf16 embedding table, 32000*256 = 8192000 ush
//   xg    : 4521984  four chunk buffers of Smax*64*768 floats [parity][dir]

typedef __attribute__((ext_vector_type(8))) short short8;    // 8 bf16 (4 VGPRs)
typedef __attribute__((ext_vector_type(4))) float floatx4;   // 4 fp32

__device__ __forceinline__ float rcp_(float x) { return __builtin_amdgcn_rcpf(x); }
__device__ __forceinline__ float sigmoid_(float x) { return rcp_(1.0f + __expf(-x)); }
__device__ __forceinline__ float tanh_(float x)    { return 1.0f - 2.0f * rcp_(1.0f + __expf(2.0f * x)); }
__device__ __forceinline__ unsigned short f2bf(float f) {     // RNE fp32->bf16
  unsigned int u = __float_as_uint(f);
  return (unsigned short)((u + 0x7fffu + ((u >> 16) & 1u)) >> 16);
}

// LDS-only barrier: waits ds ops, leaves global stores/loads in flight.
__device__ __forceinline__ void ldsbar() {
  asm volatile("s_waitcnt lgkmcnt(0)" ::: "memory");
  __builtin_amdgcn_s_barrier();
  asm volatile("" ::: "memory");
}

// ---------------- prep kernels ----------------

__global__ __launch_bounds__(256) void prep_embB(
    const float* __restrict__ emb, unsigned short* __restrict__ embB) {
  int i4 = blockIdx.x * 256 + threadIdx.x;       // 0 .. 2047999 (float4 units)
  float4 v = ((const float4*)emb)[i4];
  ushort4 o;
  o.x = f2bf(v.x); o.y = f2bf(v.y); o.z = f2bf(v.z); o.w = f2bf(v.w);
  ((ushort4*)embB)[i4] = o;
}

// Wih -> bf16 MFMA B-frags. [dir][kc][nt][lane][jj]: B[k][n]=Wih[n][k],
// n = nt*16 + (lane&15), k = kc*32 + (lane>>4)*8 + jj.
__global__ __launch_bounds__(256) void prep_packB(
    const float* __restrict__ wf, const float* __restrict__ wb,
    unsigned short* __restrict__ oB) {
  int idx = blockIdx.x * 256 + threadIdx.x;      // 0 .. 2*196608-1
  int d = idx >= 196608;
  int o = idx - d * 196608;
  int jj   = o & 7;
  int lane = (o >> 3) & 63;
  int rest = o >> 9;                             // 0..383 = kc*48 + nt
  int nt   = rest % 48;
  int kc   = rest / 48;
  int n = nt * 16 + (lane & 15);
  int k = kc * 32 + ((lane >> 4) << 3) + jj;
  const float* w = d ? wb : wf;
  oB[idx] = f2bf(w[n * 256 + k]);
}

// Whh -> bf16 MFMA A-frags.
// pA[dir][tile(48)][kc(8)][lane(64)][jj(8)]: row = tile*16 + (lane&15),
// k = kc*32 + (lane>>4)*8 + jj.
__global__ __launch_bounds__(256) void prep_packA(
    const float* __restrict__ wf, const float* __restrict__ wb,
    unsigned short* __restrict__ oA) {
  int idx = blockIdx.x * 256 + threadIdx.x;      // 0 .. 2*196608-1
  int d = idx >= 196608;
  int o = idx - d * 196608;
  int jj   = o & 7;
  int lane = (o >> 3) & 63;
  int kc   = (o >> 9) & 7;
  int tl   = o >> 12;                            // 0..47
  int row  = tl * 16 + (lane & 15);
  int k    = kc * 32 + ((lane >> 4) << 3) + jj;
  const float* w = d ? wb : wf;
  oA[idx] = f2bf(w[row * 256 + k]);
}

// ---------------- fused launch: scan(chunk c) + xg_gemm(chunk c+1) --------
// Blocks [0, nscan): recurrent scan, 1024 thr / 16 waves (gate-grouped,
// one lgkm barrier). Blocks [nscan, ...): xg GEMM for the next chunk,
// 1024 thr / 16 waves, B staged in LDS.
__global__ __launch_bounds__(1024, 4) void fused_step(
    const int* __restrict__ seq, const int* __restrict__ lens,
    const unsigned short* __restrict__ embB,
    const unsigned short* __restrict__ pWihB,
    const unsigned short* __restrict__ pA,
    const float* __restrict__ bih_f, const float* __restrict__ bih_b,
    const float* __restrict__ bhh_f, const float* __restrict__ bhh_b,
    float* __restrict__ out, float* __restrict__ hcar,
    const float* __restrict__ xs_f, const float* __restrict__ xs_b,  // scan reads
    float* __restrict__ xw_f, float* __restrict__ xw_b,              // xg writes
    int nscan, int s_base_f, int s_base_b, int Tc, int is_last, int do_add,
    int xg_on, int x_base_f, int x_base_b) {
  __shared__ __align__(16) unsigned char smem[49152];
  // scan layout: [0,2304) hbf (2 parities x 576 ush, stride 288/batch);
  //              [2304, 2304+6144) res (1536 fl, [wv][g][b][16]).
  // xg branch uses [0, 49152) as Bs4.
  const int bid = (int)blockIdx.x;
  const int tid = threadIdx.x;
  const int lane = tid & 63;

  if (bid < nscan) {
    // ------------- recurrent scan (16 waves, gate-grouped) --------------
    __builtin_amdgcn_s_setprio(1);               // favor scan over co-resident xg
    const int wv  = tid >> 6;                    // 0..15
    const int qp  = bid >> 1;                    // batch pair
    const int dir = bid & 1;
    const int b0  = qp * 2;

    const float* xg  = dir ? xs_b : xs_f;
    const float* bhh = dir ? bhh_b : bhh_f;
    const int len0 = lens[b0], len1 = lens[b0 + 1];
    const int lenmax = len0 > len1 ? len0 : len1;
    const int base = dir ? s_base_b : s_base_f;

    // Resident A-fragments: wave wv owns tiles tl = g*16 + wv (g = gate).
    // 3 tiles x 8 k-chunks x 4 VGPRs = 96 regs of fragment state.
    short8 af[3][8];
    {
      const short8* pA8 = (const short8*)(pA + (size_t)dir * 196608);
#pragma unroll
      for (int g = 0; g < 3; ++g) {
        const int tl = g * 16 + wv;
#pragma unroll
        for (int kc = 0; kc < 8; ++kc)
          af[g][kc] = pA8[((tl * 8 + kc) << 6) + lane];
      }
    }

    unsigned short* hbf = (unsigned short*)smem;        // [parity][b][288]
    float*          res = (float*)(smem + 2304);        // [wv][g][b][16]

    // Epilogue identity: lanes 0..31 own one cell (b = lane>>4, j = wv*16+jl).
    const bool epi = lane < 32;
    const int b  = (lane >> 4) & 1;
    const int jl = lane & 15;
    const int j  = wv * 16 + jl;
    const int bb = b0 + b;
    const int blen = b ? len1 : len0;
    float hreg = 0.f;
    if (epi) hreg = hcar[dir * 16384 + bb * 256 + j];
    const float bhn = bhh[512 + j];                     // r,z biases folded in xg
    if (epi) hbf[b * 288 + j] = f2bf(hreg);             // parity 0
    __syncthreads();                                    // full drain once

    int s_lo, s_hi;
    if (dir == 0) { s_lo = 0; int e = lenmax - base; s_hi = e < 0 ? 0 : (e > Tc ? Tc : e); }
    else { int sk = base + Tc - lenmax; s_lo = sk < 0 ? 0 : (sk > Tc ? Tc : sk); s_hi = Tc; }

    const int nB = lane & 15, qq = lane >> 4;
    const bool bld = nB < 2;                            // 8 lanes/wave carry B data
    const unsigned short* hsrc0 = &hbf[nB * 288 + qq * 8];
    const floatx4 ZERO4 = {0.f, 0.f, 0.f, 0.f};         // persistent MFMA C for kc=0

    // Preload first step's epilogue operands (epi lanes only).
    float xr = 0.f, xz = 0.f, xn = 0.f, oprev = 0.f;
    if (epi && s_lo < s_hi) {
      const int t0  = dir ? (base + (Tc - 1 - s_lo)) : (base + s_lo);
      const float* xrow = xg + ((size_t)(t0 - base) * 64 + bb) * 768;
      xr = xrow[j]; xz = xrow[256 + j]; xn = xrow[512 + j];
      if (do_add) oprev = out[((size_t)t0 * 64 + bb) * 256 + j];
    }

    int p = 0;
    for (int s = s_lo; s < s_hi; ++s) {
      const int t  = dir ? (base + (Tc - 1 - s)) : (base + s);
      const bool act = t < blen;

      // Prefetch NEXT step's operands; consumed next iteration.
      const int sn = (s + 1 < s_hi) ? s + 1 : s;
      const int tn = dir ? (base + (Tc - 1 - sn)) : (base + sn);
      float xr2 = 0.f, xz2 = 0.f, xn2 = 0.f, oprev2 = 0.f;
      if (epi) {
        const float* xrow = xg + ((size_t)(tn - base) * 64 + bb) * 768;
        xr2 = xrow[j]; xz2 = xrow[256 + j]; xn2 = xrow[512 + j];
        if (do_add) oprev2 = out[((size_t)tn * 64 + bb) * 256 + j];
      }

      const unsigned short* hsrc = hsrc0 + p * 576;

      // 1-ahead pipelined B-frag reads; kc=0 accumulates onto ZERO4 (D!=C),
      // so no per-step accumulator zero-init is needed.
      floatx4 acc[3];
      short8 b_cur = {0, 0, 0, 0, 0, 0, 0, 0};
      if (bld) b_cur = *(const short8*)(hsrc);
#pragma unroll
      for (int kc = 0; kc < 8; ++kc) {
        short8 b_nxt = {0, 0, 0, 0, 0, 0, 0, 0};
        if (kc < 7 && bld) b_nxt = *(const short8*)(hsrc + (kc + 1) * 32);
        if (kc == 0) {
#pragma unroll
          for (int g = 0; g < 3; ++g)
            acc[g] = __builtin_amdgcn_mfma_f32_16x16x32_bf16(af[g][0], b_cur, ZERO4, 0, 0, 0);
        } else {
#pragma unroll
          for (int g = 0; g < 3; ++g)
            acc[g] = __builtin_amdgcn_mfma_f32_16x16x32_bf16(af[g][kc], b_cur, acc[g], 0, 0, 0);
        }
        b_cur = b_nxt;
      }

      // Same-wave res bounce: D col = lane&15 (batch), row = qq*4+reg = jl.
      // Wave-private region; in-wave lgkm ordering, NO barrier needed.
      if (bld) {
#pragma unroll
        for (int g = 0; g < 3; ++g)
          *(floatx4*)&res[(((wv * 3 + g) * 2 + nB) << 4) + qq * 4] = acc[g];
      }
      float ar = res[(((wv * 3 + 0) * 2 + b) << 4) + jl];
      float az = res[(((wv * 3 + 1) * 2 + b) << 4) + jl];
      float an = res[(((wv * 3 + 2) * 2 + b) << 4) + jl];

      // epilogue (epi lanes): xr/xz include bih+bhh; xn includes bih.
      if (epi) {
        float r  = sigmoid_(xr + ar);
        float z  = sigmoid_(xz + az);
        float nn = tanh_(xn + r * (an + bhn));
        float hn = (1.0f - z) * nn + z * hreg;
        if (act) hreg = hn;
        hbf[((p ^ 1) * 576) + b * 288 + j] = f2bf(hreg);
        if (act) out[((size_t)t * 64 + bb) * 256 + j] = do_add ? (oprev + hn) : hn;
      }
      ldsbar();                                         // lgkm-only step barrier
      p ^= 1;

      xr = xr2; xz = xz2; xn = xn2; oprev = oprev2;
    }

    if (epi) {
      hcar[dir * 16384 + bb * 256 + j] = hreg;
      if (is_last)
        out[(size_t)1024 * 64 * 256 + (size_t)dir * 16384 + bb * 256 + j] = hreg;
    }

  } else if (xg_on) {
    // ---------------- xg GEMM for the NEXT chunk (16 waves) -------------
    const int idx  = bid - nscan;                // 0 .. 2*S_next-1
    const int sx   = idx >> 1;
    const int dir  = idx & 1;
    const int w    = tid >> 6;                   // 0..15
    const int mt   = w & 3;                      // m-tile (batch group)
    const int ng   = w >> 2;                     // n-quarter
    const int t    = (dir ? x_base_b : x_base_f) + sx;
    const int c    = lane & 15, qq = lane >> 4;

    const float* bih = dir ? bih_b : bih_f;
    const float* bhh = dir ? bhh_b : bhh_f;
    float* xgo = (dir ? xw_b : xw_f) + (size_t)sx * 64 * 768;

    // A-frags: token row for m = lane&15 of m-tile mt; prefetch all 8 kc.
    const int tk = seq[t * 64 + mt * 16 + c];
    const unsigned short* aptr = embB + (size_t)tk * 256 + qq * 8;
    short8 afr[8];
#pragma unroll
    for (int kc = 0; kc < 8; ++kc) afr[kc] = *(const short8*)(aptr + kc * 32);

    float4* Bs4 = (float4*)smem;                 // 3072 float4 = 48 KB

    floatx4 acc[12];
#pragma unroll
    for (int q = 0; q < 12; ++q) acc[q] = (floatx4){0.f, 0.f, 0.f, 0.f};

    for (int kc = 0; kc < 8; ++kc) {
      __syncthreads();
      const float4* src = (const float4*)(pWihB + (size_t)dir * 196608 + kc * 24576);
#pragma unroll
      for (int i = 0; i < 3; ++i) Bs4[tid + i * 1024] = src[tid + i * 1024];
      __syncthreads();
      const short8* bsv = (const short8*)Bs4;
      short8 af = afr[kc];
#pragma unroll
      for (int q = 0; q < 12; ++q) {
        int nt = ng * 12 + q;
        acc[q] = __builtin_amdgcn_mfma_f32_16x16x32_bf16(af, bsv[nt * 64 + lane], acc[q], 0, 0, 0);
      }
    }

    // D: col = lane&15 (n within tile), row = qq*4+reg (m = batch in tile).
    // Bias: bih everywhere + bhh folded for the r,z gates (n < 512).
#pragma unroll
    for (int q = 0; q < 12; ++q) {
      int n = (ng * 12 + q) * 16 + c;
      float bv = bih[n] + (n < 512 ? bhh[n] : 0.0f);
#pragma unroll
      for (int r = 0; r < 4; ++r)
        xgo[(size_t)(mt * 16 + qq * 4 + r) * 768 + n] = acc[q][r] + bv;
    }
  }
}

extern "C" void kernel_launch(void* const* d_in, const int* in_sizes, int n_in,
                              void* d_out, int out_size, void* d_ws, size_t ws_size,
                              hipStream_t stream) {
  const int*   seq   = (const int*)d_in[0];
  const int*   lens  = (const int*)d_in[1];
  const float* emb   = (const float*)d_in[2];
  const float* Wih_f = (const float*)d_in[3];
  const float* Whh_f = (const float*)d_in[4];
  const float* bih_f = (const float*)d_in[5];
  const float* bhh_f = (const float*)d_in[6];
  const float* Wih_b = (const float*)d_in[7];
  const float* Whh_b = (const float*)d_in[8];
  const float* bih_b = (const float*)d_in[9];
  const float* bhh_b = (const float*)d_in[10];
  float* out = (float*)d_out;
  float* ws  = (float*)d_ws;

  float*          hcar   = ws;
  unsigned short* pA     = (unsigned short*)(ws + 32768);
  unsigned short* pWihB  = (unsigned short*)(ws + 229376);
  unsigned short* embB   = (unsigned short*)(ws + 425984);
  float*          xgbase = ws + 4521984;

  // Chunk plan: palindromic sizes, even count (keeps do_add mirror logic).
  int S[128], off[128], C = 0, Smax = 0;
  {
    size_t needA = (4521984ull + 4ull * 224ull * 49152ull) * 4ull;
    if (needA <= ws_size) {
      const int plan[6] = {64, 224, 224, 224, 224, 64};
      C = 6;
      for (int i = 0; i < C; ++i) S[i] = plan[i];
    } else {
      const int cands[7] = {512, 256, 128, 64, 32, 16, 8};
      int Tc = 8;
      for (int i = 0; i < 7; ++i) {
        size_t need = (4521984ull + 4ull * (size_t)cands[i] * 49152ull) * 4ull;
        if (need <= ws_size) { Tc = cands[i]; break; }
      }
      C = 1024 / Tc;
      for (int i = 0; i < C; ++i) S[i] = Tc;
    }
    int o = 0;
    for (int i = 0; i < C; ++i) { off[i] = o; o += S[i]; if (S[i] > Smax) Smax = S[i]; }
  }

  float* xb[2][2];                               // [parity][dir]
  for (int p = 0; p < 2; ++p)
    for (int d = 0; d < 2; ++d)
      xb[p][d] = xgbase + ((size_t)(p * 2 + d)) * Smax * 49152;

  hipMemsetAsync(d_out, 0, (size_t)1024 * 64 * 256 * 4, stream);  // masked outputs stay 0
  hipMemsetAsync(hcar, 0, 32768ull * 4ull, stream);               // initial h = 0
  prep_embB<<<dim3(8000), dim3(256), 0, stream>>>(emb, embB);
  prep_packB<<<dim3(1536), dim3(256), 0, stream>>>(Wih_f, Wih_b, pWihB);
  prep_packA<<<dim3(1536), dim3(256), 0, stream>>>(Whh_f, Whh_b, pA);

  // Prologue: xg for launch 0 only (fwd chunk 0, bwd chunk C-1) -> parity 0.
  fused_step<<<dim3(2 * S[0]), dim3(1024), 0, stream>>>(
      seq, lens, embB, pWihB, pA, bih_f, bih_b, bhh_f, bhh_b, out, hcar,
      xb[0][0], xb[0][1], xb[0][0], xb[0][1],
      /*nscan=*/0, 0, 0, /*Tc=*/S[0], 0, 0,
      /*xg_on=*/1, /*x_base_f=*/off[0], /*x_base_b=*/off[C - 1]);

  // Pipeline: launch c runs scan(fwd chunk c, bwd chunk C-1-c) on blocks
  // [0,64) and xg for launch c+1 on blocks [64, 64+2*S[c+1]).
  for (int c = 0; c < C; ++c) {
    int xgon = (c + 1 < C) ? 1 : 0;
    int nblk = 64 + (xgon ? 2 * S[c + 1] : 0);
    fused_step<<<dim3(nblk), dim3(1024), 0, stream>>>(
        seq, lens, embB, pWihB, pA, bih_f, bih_b, bhh_f, bhh_b, out, hcar,
        xb[c & 1][0], xb[c & 1][1], xb[(c + 1) & 1][0], xb[(c + 1) & 1][1],
        /*nscan=*/64, /*s_base_f=*/off[c], /*s_base_b=*/off[C - 1 - c], /*Tc=*/S[c],
        /*is_last=*/(c == C - 1) ? 1 : 0, /*do_add=*/(2 * c >= C) ? 1 : 0,
        xgon, /*x_base_f=*/xgon ? off[c + 1] : 0, /*x_base_b=*/xgon ? off[C - 2 - c] : 0);
  }
}